// Round 9
// baseline (225.878 us; speedup 1.0000x reference)
//
#include <hip/hip_runtime.h>

typedef __attribute__((ext_vector_type(8))) short bf16x8;
typedef __attribute__((ext_vector_type(16))) float f32x16;

#define NROWS 32768
#define KC 1024
#define DD 128
#define EPS_GAP 1e-3f
#define FLT_BIG 3.4e38f

typedef const unsigned int __attribute__((address_space(1)))* gp1_t;
typedef unsigned int __attribute__((address_space(3)))* lp3_t;

__device__ __forceinline__ unsigned short f2bf(float f) {
    unsigned u = __float_as_uint(f);
    unsigned r = u + 0x7FFFu + ((u >> 16) & 1u);
    return (unsigned short)(r >> 16);
}
__device__ __forceinline__ float bf2f(unsigned short h) {
    return __uint_as_float(((unsigned)h) << 16);
}

// ========= prep: codedist(128) | x-frag conv(512) | e-frags(128) | s2(4) =========
// xf layout (shorts): row*256 + kd*32 + [hi: d-order 16] [lo: 16]
// a_sw layout (shorts): frag(ct,kd,term)=((ct*8+kd)*2+term)*512; lane l: code ct*32+(l&31), d=kd*16+(l>>5)*8+j
__global__ __launch_bounds__(256) void k_prep_cd(const float* __restrict__ e,
                                                 const float* __restrict__ x,
                                                 unsigned short* __restrict__ a_sw,
                                                 unsigned short* __restrict__ xf,
                                                 float* __restrict__ eT,
                                                 float* __restrict__ s2g,
                                                 float* __restrict__ out_scales) {
    const int b = blockIdx.x, tid = threadIdx.x;
    if (b < 128) {
        // ---- codedist: 8 codes/block, exact fp32 diff-square ----
        __shared__ float ek[8][DD];          // 4 KB
        __shared__ float r0w[8][4], r1w[8][4];
        __shared__ float scsh[8];
        const int kb = b * 8;
        #pragma unroll
        for (int i = 0; i < 4; i++) {
            int idx = i * 256 + tid;
            int ki = idx & 7, d = idx >> 3;
            ek[ki][d] = e[(size_t)d * KC + kb + ki];
        }
        __syncthreads();
        const int j0 = tid * 4;
        float acc[8][4];
        #pragma unroll
        for (int ki = 0; ki < 8; ki++)
            #pragma unroll
            for (int jj = 0; jj < 4; jj++) acc[ki][jj] = 0.f;
        #pragma unroll 2
        for (int dc = 0; dc < 32; dc++) {
            int d0 = dc * 4;
            float4 ev[4];
            #pragma unroll
            for (int dd = 0; dd < 4; dd++)
                ev[dd] = *(const float4*)&e[(size_t)(d0 + dd) * KC + j0];
            #pragma unroll
            for (int ki = 0; ki < 8; ki++) {
                float4 ekv = *(const float4*)&ek[ki][d0];
                const float* ekp = (const float*)&ekv;
                #pragma unroll
                for (int dd = 0; dd < 4; dd++) {
                    const float* evp = (const float*)&ev[dd];
                    #pragma unroll
                    for (int jj = 0; jj < 4; jj++) {
                        float t = ekp[dd] - evp[jj];
                        acc[ki][jj] = fmaf(t, t, acc[ki][jj]);
                    }
                }
            }
        }
        float m0[8], m1[8];
        #pragma unroll
        for (int ki = 0; ki < 8; ki++) {
            m0[ki] = FLT_BIG; m1[ki] = FLT_BIG;
            #pragma unroll
            for (int jj = 0; jj < 4; jj++) {
                float dd = acc[ki][jj];
                if (dd < m0[ki]) { m1[ki] = m0[ki]; m0[ki] = dd; }
                else if (dd < m1[ki]) m1[ki] = dd;
            }
        }
        #pragma unroll
        for (int msk = 1; msk < 64; msk <<= 1) {
            #pragma unroll
            for (int ki = 0; ki < 8; ki++) {
                float u0 = __shfl_xor(m0[ki], msk, 64);
                float u1 = __shfl_xor(m1[ki], msk, 64);
                if (u0 < m0[ki]) { m1[ki] = fminf(m0[ki], u1); m0[ki] = u0; }
                else             { m1[ki] = fminf(m1[ki], u0); }
            }
        }
        const int w = tid >> 6;
        if ((tid & 63) == 0) {
            #pragma unroll
            for (int ki = 0; ki < 8; ki++) { r0w[ki][w] = m0[ki]; r1w[ki][w] = m1[ki]; }
        }
        __syncthreads();
        if (tid < 8) {
            float a0 = FLT_BIG, a1 = FLT_BIG;
            #pragma unroll
            for (int ww = 0; ww < 4; ww++) {
                float v0 = r0w[tid][ww], v1 = r1w[tid][ww];
                if (v0 < a0) { a1 = fminf(a0, v1); a0 = v0; }
                else a1 = fminf(a1, v0);
            }
            scsh[tid] = a1 * (1.0f / 64.0f);   // second_smallest / (D/2)
        }
        __syncthreads();
        if (tid < 128) {
            #pragma unroll
            for (int ki = 0; ki < 8; ki++)
                out_scales[(size_t)(kb + ki) * DD + tid] = scsh[ki];
        }
    } else if (b < 640) {
        // ---- x -> bf16 hi/lo B-fragment layout (64 rows/block) ----
        const int row0 = (b - 128) * 64;
        #pragma unroll
        for (int it = 0; it < 2; it++) {
            int idx = it * 256 + tid;
            int rl = idx >> 3, kd = idx & 7;
            const float* p = x + (size_t)(row0 + rl) * DD + kd * 16;
            float4 v4[4];
            #pragma unroll
            for (int i = 0; i < 4; i++) v4[i] = *(const float4*)(p + i * 4);
            const float* v = (const float*)v4;
            bf16x8 h0, h1, l0, l1;
            #pragma unroll
            for (int j = 0; j < 8; j++) {
                unsigned short hh = f2bf(v[j]);
                h0[j] = (short)hh; l0[j] = (short)f2bf(v[j] - bf2f(hh));
                unsigned short hh2 = f2bf(v[8 + j]);
                h1[j] = (short)hh2; l1[j] = (short)f2bf(v[8 + j] - bf2f(hh2));
            }
            unsigned short* o = xf + (size_t)(row0 + rl) * 256 + kd * 32;
            *(bf16x8*)(o + 0)  = h0;
            *(bf16x8*)(o + 8)  = h1;
            *(bf16x8*)(o + 16) = l0;
            *(bf16x8*)(o + 24) = l1;
        }
    } else if (b < 768) {
        // ---- e -> bf16 hi/lo A-fragment layout + eT ----
        const int t = (b - 640) * 2 + (tid >> 7);     // tile 0..255
        const int ct = t >> 3, kd = t & 7;
        const int tt = tid & 127;
        const int m = tt & 31, dg = tt >> 5;
        const int c = ct * 32 + m;
        const int d0 = kd * 16 + dg * 4;
        float v[4]; short hi[4], lo[4];
        #pragma unroll
        for (int jj = 0; jj < 4; jj++) {
            float f = e[(size_t)(d0 + jj) * KC + c];
            v[jj] = f;
            unsigned short hh = f2bf(f);
            hi[jj] = (short)hh;
            lo[jj] = (short)f2bf(f - bf2f(hh));
        }
        const int h = dg >> 1, jb = (dg & 1) * 4;
        size_t base = ((size_t)(ct * 8 + kd) * 2) * 512 + (h * 32 + m) * 8 + jb;
        *(short4*)&a_sw[base]       = make_short4(hi[0], hi[1], hi[2], hi[3]);
        *(short4*)&a_sw[base + 512] = make_short4(lo[0], lo[1], lo[2], lo[3]);
        *(float4*)&eT[(size_t)c * DD + d0] = make_float4(v[0], v[1], v[2], v[3]);
    } else {
        const int c = (b - 768) * 256 + tid;
        float s = 0.f;
        #pragma unroll 8
        for (int d = 0; d < DD; d++) { float f = e[(size_t)d * KC + c]; s = fmaf(f, f, s); }
        s2g[c] = s;
    }
}

// ================= main: 128 rows x 128 codes per block =================
__global__ __launch_bounds__(256, 2) void k_main(const unsigned short* __restrict__ xf,
                                                 const unsigned short* __restrict__ a_sw,
                                                 const float* __restrict__ s2g,
                                                 float* __restrict__ pv0,
                                                 float* __restrict__ pv1,
                                                 int* __restrict__ pi0) {
    __shared__ short es[32768];     // 64 KB
    __shared__ float s2s[128];

    const int tid = threadIdx.x;
    const int w = tid >> 6, lane = tid & 63;
    const int halfk = lane >> 5, col = lane & 31;
    const int g = blockIdx.x >> 8;
    const int rg = blockIdx.x & 255;
    const int myrow = rg * 128 + w * 32 + col;

    {
        const char* src = (const char*)a_sw + (size_t)g * 65536;
        char* dst = (char*)es;
        #pragma unroll
        for (int it = 0; it < 16; it++) {
            int off = (it * 256 + tid) * 16;
            __builtin_amdgcn_global_load_lds((gp1_t)(const void*)(src + off),
                                             (lp3_t)(void*)(dst + off), 16, 0, 0);
        }
    }
    if (tid < 128) s2s[tid] = s2g[g * 128 + tid];

    // x fragments: direct 16-B loads from pre-converted xf
    bf16x8 xh[8], xl[8];
    {
        const unsigned short* xfr = xf + (size_t)myrow * 256 + halfk * 8;
        #pragma unroll
        for (int kd = 0; kd < 8; kd++) {
            xh[kd] = *(const bf16x8*)(xfr + kd * 32);
            xl[kd] = *(const bf16x8*)(xfr + kd * 32 + 16);
        }
    }
    __syncthreads();   // one drain for the whole kernel

    float bv0 = FLT_BIG, bv1 = FLT_BIG;
    int bi0 = 0x7fffffff;

    #pragma unroll 1
    for (int ct = 0; ct < 4; ct++) {
        f32x16 accA, accB, accC;
        #pragma unroll
        for (int r = 0; r < 16; r++) { accA[r] = 0.f; accB[r] = 0.f; accC[r] = 0.f; }

        #pragma unroll
        for (int kd = 0; kd < 8; kd++) {
            const short* fp = &es[((ct * 8 + kd) * 2) * 512 + lane * 8];
            bf16x8 ahi = *(const bf16x8*)fp;
            bf16x8 alo = *(const bf16x8*)(fp + 512);
            accA = __builtin_amdgcn_mfma_f32_32x32x16_bf16(ahi, xh[kd], accA, 0, 0, 0);
            accB = __builtin_amdgcn_mfma_f32_32x32x16_bf16(alo, xh[kd], accB, 0, 0, 0);
            accC = __builtin_amdgcn_mfma_f32_32x32x16_bf16(ahi, xl[kd], accC, 0, 0, 0);
        }

        int clb = ct * 32 + 4 * halfk;
        #pragma unroll
        for (int g8 = 0; g8 < 4; g8++) {
            float4 s2v = *(const float4*)&s2s[clb + g8 * 8];
            const float* s2p = (const float*)&s2v;
            #pragma unroll
            for (int q = 0; q < 4; q++) {
                int r = g8 * 4 + q;
                float sim = (accA[r] + accB[r]) + accC[r];
                float dv = fmaf(-2.f, sim, s2p[q]);
                int ci = g * 128 + clb + g8 * 8 + q;
                bool lt = dv < bv0;
                bv1 = fminf(bv1, fmaxf(bv0, dv));
                bv0 = fminf(bv0, dv);
                bi0 = lt ? ci : bi0;
            }
        }
    }

    float u0 = __shfl_xor(bv0, 32, 64);
    float u1 = __shfl_xor(bv1, 32, 64);
    int   j0 = __shfl_xor(bi0, 32, 64);
    float v0, v1; int i0;
    if (u0 < bv0 || (u0 == bv0 && j0 < bi0)) { v0 = u0; i0 = j0; v1 = fminf(u1, bv0); }
    else                                     { v0 = bv0; i0 = bi0; v1 = fminf(bv1, u0); }

    if (lane < 32) {
        size_t o = (size_t)myrow * 8 + g;    // AoS: coalesced reads in k_post
        pv0[o] = v0; pv1[o] = v1; pi0[o] = i0;
    }
}

// ============ post: merge + gather + loss partial + inline fix ============
// 256 blocks x 128 rows: 4 independent row-batches per thread for ILP.
__global__ __launch_bounds__(256) void k_post(const float* __restrict__ x,
                                              const float* __restrict__ e,
                                              const float* __restrict__ eT,
                                              const float* __restrict__ s2g,
                                              const float* __restrict__ pv0,
                                              const float* __restrict__ pv1,
                                              const int* __restrict__ pi0,
                                              float* __restrict__ out_q,
                                              double* __restrict__ partial) {
    __shared__ int   kml_l[128];
    __shared__ int   flist_l[128];
    __shared__ int   cnt;
    __shared__ float xrow[DD];
    __shared__ float rv[256];
    __shared__ int   ri[256];
    __shared__ int   kfix;
    __shared__ float wsum[4];
    const int tid = threadIdx.x;
    const int w = tid >> 6, lane = tid & 63;
    const int row0 = blockIdx.x * 128;

    if (tid == 0) cnt = 0;
    __syncthreads();

    // ---- phase 1: merge 8 group-partials per row, 4 batches unrolled ----
    {
        const int rl = tid >> 3;             // local row within batch
        float v0[4], v1[4]; int i0[4];
        #pragma unroll
        for (int bt = 0; bt < 4; bt++) {
            size_t o = (size_t)(row0 + bt * 32) * 8 + tid;   // coalesced
            v0[bt] = pv0[o]; v1[bt] = pv1[o]; i0[bt] = pi0[o];
        }
        #pragma unroll
        for (int msk = 1; msk < 8; msk <<= 1) {
            #pragma unroll
            for (int bt = 0; bt < 4; bt++) {
                float u0 = __shfl_xor(v0[bt], msk, 64);
                float u1 = __shfl_xor(v1[bt], msk, 64);
                int   j0 = __shfl_xor(i0[bt], msk, 64);
                if (u0 < v0[bt] || (u0 == v0[bt] && j0 < i0[bt])) {
                    v1[bt] = fminf(v0[bt], u1); v0[bt] = u0; i0[bt] = j0;
                } else v1[bt] = fminf(v1[bt], u0);
            }
        }
        if ((tid & 7) == 0) {
            #pragma unroll
            for (int bt = 0; bt < 4; bt++) {
                int flag = (v1[bt] - v0[bt] < EPS_GAP) ? 1 : 0;
                kml_l[bt * 32 + rl] = i0[bt] | (flag << 31);
                if (flag) { int s = atomicAdd(&cnt, 1); flist_l[s] = bt * 32 + rl; }
            }
        }
    }
    __syncthreads();

    // ---- phase 2: element-parallel gather + loss, 4 batches unrolled ----
    float lsum = 0.f;
    {
        const int rl = tid >> 3, seg = (tid & 7) * 16;
        int pk[4];
        #pragma unroll
        for (int bt = 0; bt < 4; bt++) pk[bt] = kml_l[bt * 32 + rl];
        #pragma unroll
        for (int bt = 0; bt < 4; bt++) {
            if (pk[bt] >= 0) {
                size_t grow = (size_t)(row0 + bt * 32 + rl);
                const float* qp = eT + (size_t)pk[bt] * DD + seg;
                const float* xp = x + grow * DD + seg;
                float* op = out_q + grow * DD + seg;
                #pragma unroll
                for (int i = 0; i < 4; i++) {
                    float4 q  = *(const float4*)(qp + i * 4);
                    float4 xv = *(const float4*)(xp + i * 4);
                    *(float4*)(op + i * 4) = q;
                    float f0 = q.x - xv.x, f1 = q.y - xv.y;
                    float f2 = q.z - xv.z, f3 = q.w - xv.w;
                    lsum = fmaf(f0, f0, lsum); lsum = fmaf(f1, f1, lsum);
                    lsum = fmaf(f2, f2, lsum); lsum = fmaf(f3, f3, lsum);
                }
            }
        }
    }

    // ---- phase 3: exact fp32 re-argmin for flagged rows (rare, uniform) ----
    const int nf = cnt;
    for (int fi = 0; fi < nf; fi++) {
        const int r = flist_l[fi];
        if (tid < 32) ((float4*)xrow)[tid] = ((const float4*)(x + (size_t)(row0 + r) * DD))[tid];
        __syncthreads();
        int c0 = tid * 4;
        float s0 = 0.f, s1 = 0.f, s2 = 0.f, s3 = 0.f;
        #pragma unroll 8
        for (int d = 0; d < DD; d++) {
            float xv = xrow[d];
            float4 ev = *(const float4*)(e + (size_t)d * KC + c0);
            s0 = fmaf(xv, ev.x, s0); s1 = fmaf(xv, ev.y, s1);
            s2 = fmaf(xv, ev.z, s2); s3 = fmaf(xv, ev.w, s3);
        }
        float dv0 = s2g[c0 + 0] - 2.f * s0;
        float dv1 = s2g[c0 + 1] - 2.f * s1;
        float dv2 = s2g[c0 + 2] - 2.f * s2;
        float dv3 = s2g[c0 + 3] - 2.f * s3;
        float bv = dv0; int bi = c0;
        if (dv1 < bv) { bv = dv1; bi = c0 + 1; }
        if (dv2 < bv) { bv = dv2; bi = c0 + 2; }
        if (dv3 < bv) { bv = dv3; bi = c0 + 3; }
        rv[tid] = bv; ri[tid] = bi;
        __syncthreads();
        if (tid == 0) {
            float b = rv[0]; int bidx = ri[0];
            for (int t = 1; t < 256; t++)
                if (rv[t] < b) { b = rv[t]; bidx = ri[t]; }
            kfix = bidx;
        }
        __syncthreads();
        if (tid < 128) {
            float q = eT[(size_t)kfix * DD + tid];
            float xv = xrow[tid];
            out_q[(size_t)(row0 + r) * DD + tid] = q;
            float f = q - xv;
            lsum = fmaf(f, f, lsum);
        }
        __syncthreads();
    }

    // ---- per-block partial loss: plain store, no atomics, no fence ----
    #pragma unroll
    for (int off = 32; off > 0; off >>= 1) lsum += __shfl_down(lsum, off, 64);
    if (lane == 0) wsum[w] = lsum;
    __syncthreads();
    if (tid == 0)
        partial[blockIdx.x] = (double)((wsum[0] + wsum[1]) + (wsum[2] + wsum[3]));
}

// ================= fin: sum 256 partials, write loss =================
__global__ __launch_bounds__(256) void k_fin(const double* __restrict__ partial,
                                             float* __restrict__ out_loss) {
    __shared__ double wred[4];
    const int tid = threadIdx.x;
    const int w = tid >> 6, lane = tid & 63;
    double s = partial[tid];
    #pragma unroll
    for (int off = 32; off > 0; off >>= 1)
        s += __shfl_down(s, off, 64);
    if (lane == 0) wred[w] = s;
    __syncthreads();
    if (tid == 0) {
        double m = ((wred[0] + wred[1]) + (wred[2] + wred[3])) / 4194304.0;
        out_loss[0] = (float)(0.25 * m + m);
    }
}

extern "C" void kernel_launch(void* const* d_in, const int* in_sizes, int n_in,
                              void* d_out, int out_size, void* d_ws, size_t ws_size,
                              hipStream_t stream) {
    const float* x = (const float*)d_in[0];
    const float* e = (const float*)d_in[1];
    float* out_q      = (float*)d_out;
    float* out_loss   = out_q + (size_t)NROWS * DD;
    float* out_scales = out_loss + 1;

    char* ws = (char*)d_ws;
    float*  s2g            = (float*)(ws + 1024);
    float*  eT             = (float*)(ws + 8192);
    unsigned short* a_sw   = (unsigned short*)(ws + 532480);
    float*  pv0            = (float*)(ws + 1056768);
    float*  pv1            = (float*)(ws + 2105344);
    int*    pi0            = (int*)(ws + 3153920);
    double* partial        = (double*)(ws + 4202496);
    unsigned short* xf     = (unsigned short*)(ws + 4210688);

    k_prep_cd<<<772, 256, 0, stream>>>(e, x, a_sw, xf, eT, s2g, out_scales);
    k_main<<<2048, 256, 0, stream>>>(xf, a_sw, s2g, pv0, pv1, pi0);
    k_post<<<NROWS / 128, 256, 0, stream>>>(x, e, eT, s2g, pv0, pv1, pi0, out_q, partial);
    k_fin<<<1, 256, 0, stream>>>(partial, out_loss);
}

// Round 10
// 148.107 us; speedup vs baseline: 1.5251x; 1.5251x over previous
//
#include <hip/hip_runtime.h>

typedef __attribute__((ext_vector_type(8))) short bf16x8;
typedef __attribute__((ext_vector_type(16))) float f32x16;

#define NROWS 32768
#define KC 1024
#define DD 128
#define EPS_GAP 1e-3f
#define FLT_BIG 3.4e38f

typedef const unsigned int __attribute__((address_space(1)))* gp1_t;
typedef unsigned int __attribute__((address_space(3)))* lp3_t;

__device__ __forceinline__ unsigned short f2bf(float f) {
    unsigned u = __float_as_uint(f);
    unsigned r = u + 0x7FFFu + ((u >> 16) & 1u);
    return (unsigned short)(r >> 16);
}
__device__ __forceinline__ float bf2f(unsigned short h) {
    return __uint_as_float(((unsigned)h) << 16);
}

// ================= prep + s2 + codedist (R8 baseline) =================
__global__ __launch_bounds__(256) void k_prep_cd(const float* __restrict__ e,
                                                 unsigned short* __restrict__ a_sw,
                                                 float* __restrict__ eT,
                                                 float* __restrict__ s2g,
                                                 float* __restrict__ out_scales) {
    const int b = blockIdx.x, tid = threadIdx.x;
    if (b < 128) {
        const int t = b * 2 + (tid >> 7);     // tile 0..255
        const int ct = t >> 3, kd = t & 7;
        const int tt = tid & 127;
        const int m = tt & 31, dg = tt >> 5;
        const int c = ct * 32 + m;
        const int d0 = kd * 16 + dg * 4;
        float v[4]; short hi[4], lo[4];
        #pragma unroll
        for (int jj = 0; jj < 4; jj++) {
            float f = e[(size_t)(d0 + jj) * KC + c];
            v[jj] = f;
            unsigned short hh = f2bf(f);
            hi[jj] = (short)hh;
            lo[jj] = (short)f2bf(f - bf2f(hh));
        }
        const int h = dg >> 1, jb = (dg & 1) * 4;
        size_t base = ((size_t)(ct * 8 + kd) * 2) * 512 + (h * 32 + m) * 8 + jb;
        *(short4*)&a_sw[base]       = make_short4(hi[0], hi[1], hi[2], hi[3]);
        *(short4*)&a_sw[base + 512] = make_short4(lo[0], lo[1], lo[2], lo[3]);
        *(float4*)&eT[(size_t)c * DD + d0] = make_float4(v[0], v[1], v[2], v[3]);
    } else if (b < 132) {
        const int c = (b - 128) * 256 + tid;
        float s = 0.f;
        #pragma unroll 8
        for (int d = 0; d < DD; d++) { float f = e[(size_t)d * KC + c]; s = fmaf(f, f, s); }
        s2g[c] = s;
    } else {
        // ---- codedist: 2 codes per block, exact fp32 diff-square ----
        __shared__ float ek[2][DD];
        __shared__ float r0w[2][4], r1w[2][4];
        __shared__ float scsh[2];
        const int kb = (b - 132) * 2;
        { int ki = tid >> 7, d = tid & 127; ek[ki][d] = e[(size_t)d * KC + kb + ki]; }
        __syncthreads();
        const int j0 = tid * 4;
        float da[2][4];
        #pragma unroll
        for (int ki = 0; ki < 2; ki++)
            #pragma unroll
            for (int jj = 0; jj < 4; jj++) da[ki][jj] = 0.f;
        #pragma unroll 2
        for (int dc = 0; dc < 32; dc++) {
            int d0 = dc * 4;
            float4 ev[4];
            #pragma unroll
            for (int dd = 0; dd < 4; dd++)
                ev[dd] = *(const float4*)&e[(size_t)(d0 + dd) * KC + j0];
            float4 ek0 = *(const float4*)&ek[0][d0];
            float4 ek1 = *(const float4*)&ek[1][d0];
            const float* e0 = (const float*)&ek0;
            const float* e1 = (const float*)&ek1;
            #pragma unroll
            for (int dd = 0; dd < 4; dd++) {
                const float* evp = (const float*)&ev[dd];
                #pragma unroll
                for (int jj = 0; jj < 4; jj++) {
                    float t0 = e0[dd] - evp[jj];
                    float t1 = e1[dd] - evp[jj];
                    da[0][jj] = fmaf(t0, t0, da[0][jj]);
                    da[1][jj] = fmaf(t1, t1, da[1][jj]);
                }
            }
        }
        float m0[2] = {FLT_BIG, FLT_BIG}, m1[2] = {FLT_BIG, FLT_BIG};
        #pragma unroll
        for (int ki = 0; ki < 2; ki++)
            #pragma unroll
            for (int jj = 0; jj < 4; jj++) {
                float dd = da[ki][jj];
                if (dd < m0[ki]) { m1[ki] = m0[ki]; m0[ki] = dd; }
                else if (dd < m1[ki]) m1[ki] = dd;
            }
        #pragma unroll
        for (int msk = 1; msk < 64; msk <<= 1) {
            #pragma unroll
            for (int ki = 0; ki < 2; ki++) {
                float u0 = __shfl_xor(m0[ki], msk, 64);
                float u1 = __shfl_xor(m1[ki], msk, 64);
                if (u0 < m0[ki]) { m1[ki] = fminf(m0[ki], u1); m0[ki] = u0; }
                else             { m1[ki] = fminf(m1[ki], u0); }
            }
        }
        const int w = tid >> 6;
        if ((tid & 63) == 0) {
            r0w[0][w] = m0[0]; r1w[0][w] = m1[0];
            r0w[1][w] = m0[1]; r1w[1][w] = m1[1];
        }
        __syncthreads();
        if (tid < 2) {
            float a0 = FLT_BIG, a1 = FLT_BIG;
            #pragma unroll
            for (int ww = 0; ww < 4; ww++) {
                float v0 = r0w[tid][ww], v1 = r1w[tid][ww];
                if (v0 < a0) { a1 = fminf(a0, v1); a0 = v0; }
                else a1 = fminf(a1, v0);
            }
            scsh[tid] = a1 * (1.0f / 64.0f);   // second_smallest / (D/2)
        }
        __syncthreads();
        if (tid < 128) {
            out_scales[(size_t)kb * DD + tid]       = scsh[0];
            out_scales[(size_t)(kb + 1) * DD + tid] = scsh[1];
        }
    }
}

// ================= main: 128 rows x 128 codes per block (R8 baseline) ============
__global__ __launch_bounds__(256, 2) void k_main(const float* __restrict__ x,
                                                 const unsigned short* __restrict__ a_sw,
                                                 const float* __restrict__ s2g,
                                                 float* __restrict__ pv0,
                                                 float* __restrict__ pv1,
                                                 int* __restrict__ pi0) {
    __shared__ short es[32768];     // 64 KB
    __shared__ float s2s[128];

    const int tid = threadIdx.x;
    const int w = tid >> 6, lane = tid & 63;
    const int halfk = lane >> 5, col = lane & 31;
    const int g = blockIdx.x >> 8;
    const int rg = blockIdx.x & 255;
    const int myrow = rg * 128 + w * 32 + col;

    {
        const char* src = (const char*)a_sw + (size_t)g * 65536;
        char* dst = (char*)es;
        #pragma unroll
        for (int it = 0; it < 16; it++) {
            int off = (it * 256 + tid) * 16;
            __builtin_amdgcn_global_load_lds((gp1_t)(const void*)(src + off),
                                             (lp3_t)(void*)(dst + off), 16, 0, 0);
        }
    }
    if (tid < 128) s2s[tid] = s2g[g * 128 + tid];

    const float* xr = x + (size_t)myrow * DD;
    bf16x8 xh[8], xl[8];
    #pragma unroll
    for (int kd = 0; kd < 8; kd++) {
        const float* p = xr + kd * 16 + halfk * 8;
        float4 a = *(const float4*)p;
        float4 b = *(const float4*)(p + 4);
        float v[8] = {a.x, a.y, a.z, a.w, b.x, b.y, b.z, b.w};
        #pragma unroll
        for (int j = 0; j < 8; j++) {
            unsigned short h = f2bf(v[j]);
            xh[kd][j] = (short)h;
            xl[kd][j] = (short)f2bf(v[j] - bf2f(h));
        }
    }
    __syncthreads();   // one drain for the whole kernel

    float bv0 = FLT_BIG, bv1 = FLT_BIG;
    int bi0 = 0x7fffffff;

    #pragma unroll 1
    for (int ct = 0; ct < 4; ct++) {
        f32x16 accA, accB, accC;
        #pragma unroll
        for (int r = 0; r < 16; r++) { accA[r] = 0.f; accB[r] = 0.f; accC[r] = 0.f; }

        #pragma unroll
        for (int kd = 0; kd < 8; kd++) {
            const short* fp = &es[((ct * 8 + kd) * 2) * 512 + lane * 8];
            bf16x8 ahi = *(const bf16x8*)fp;
            bf16x8 alo = *(const bf16x8*)(fp + 512);
            accA = __builtin_amdgcn_mfma_f32_32x32x16_bf16(ahi, xh[kd], accA, 0, 0, 0);
            accB = __builtin_amdgcn_mfma_f32_32x32x16_bf16(alo, xh[kd], accB, 0, 0, 0);
            accC = __builtin_amdgcn_mfma_f32_32x32x16_bf16(ahi, xl[kd], accC, 0, 0, 0);
        }

        int clb = ct * 32 + 4 * halfk;
        #pragma unroll
        for (int g8 = 0; g8 < 4; g8++) {
            float4 s2v = *(const float4*)&s2s[clb + g8 * 8];
            const float* s2p = (const float*)&s2v;
            #pragma unroll
            for (int q = 0; q < 4; q++) {
                int r = g8 * 4 + q;
                float sim = (accA[r] + accB[r]) + accC[r];
                float dv = fmaf(-2.f, sim, s2p[q]);
                int ci = g * 128 + clb + g8 * 8 + q;
                bool lt = dv < bv0;
                bv1 = fminf(bv1, fmaxf(bv0, dv));
                bv0 = fminf(bv0, dv);
                bi0 = lt ? ci : bi0;
            }
        }
    }

    float u0 = __shfl_xor(bv0, 32, 64);
    float u1 = __shfl_xor(bv1, 32, 64);
    int   j0 = __shfl_xor(bi0, 32, 64);
    float v0, v1; int i0;
    if (u0 < bv0 || (u0 == bv0 && j0 < bi0)) { v0 = u0; i0 = j0; v1 = fminf(u1, bv0); }
    else                                     { v0 = bv0; i0 = bi0; v1 = fminf(bv1, u0); }

    if (lane < 32) {
        size_t o = (size_t)myrow * 8 + g;    // AoS: coalesced reads in k_post
        pv0[o] = v0; pv1[o] = v1; pi0[o] = i0;
    }
}

// ============ post: shuffle-merge + gather + loss partial + inline fix ============
// 2048 blocks x 128 threads, 16 rows/block. No LDS between merge and gather.
__global__ __launch_bounds__(128) void k_post(const float* __restrict__ x,
                                              const float* __restrict__ e,
                                              const float* __restrict__ eT,
                                              const float* __restrict__ s2g,
                                              const float* __restrict__ pv0,
                                              const float* __restrict__ pv1,
                                              const int* __restrict__ pi0,
                                              float* __restrict__ out_q,
                                              double* __restrict__ partial) {
    __shared__ int   flist_l[16];
    __shared__ int   cnt;
    __shared__ float xrow[DD];
    __shared__ float rv[128];
    __shared__ int   ri[128];
    __shared__ int   kfix;
    __shared__ float wsum[2];
    const int tid = threadIdx.x;
    const int w = tid >> 6, lane = tid & 63;
    const int row0 = blockIdx.x * 16;
    const int rl = tid >> 3;                 // local row 0..15
    const int seg = (tid & 7) * 16;          // 16 consecutive floats

    if (tid == 0) cnt = 0;

    // ---- prefetch x segment (independent of merge chain) ----
    const size_t grow = (size_t)(row0 + rl);
    float4 xv[4];
    {
        const float* xp = x + grow * DD + seg;
        #pragma unroll
        for (int i = 0; i < 4; i++) xv[i] = *(const float4*)(xp + i * 4);
    }

    // ---- merge 8 group-partials (every lane ends with its row's result) ----
    float v0, v1; int i0;
    {
        size_t o = (size_t)row0 * 8 + tid;   // == (row0+rl)*8 + g, coalesced
        v0 = pv0[o]; v1 = pv1[o]; i0 = pi0[o];
        #pragma unroll
        for (int msk = 1; msk < 8; msk <<= 1) {
            float u0 = __shfl_xor(v0, msk, 64);
            float u1 = __shfl_xor(v1, msk, 64);
            int   j0 = __shfl_xor(i0, msk, 64);
            if (u0 < v0 || (u0 == v0 && j0 < i0)) { v1 = fminf(v0, u1); v0 = u0; i0 = j0; }
            else v1 = fminf(v1, u0);
        }
    }
    const int flagged = (v1 - v0 < EPS_GAP) ? 1 : 0;
    if ((tid & 7) == 0 && flagged) { int s = atomicAdd(&cnt, 1); flist_l[s] = rl; }

    // ---- gather + loss (skip flagged rows; rewritten in fix phase) ----
    float lsum = 0.f;
    if (!flagged) {
        const float* qp = eT + (size_t)i0 * DD + seg;
        float* op = out_q + grow * DD + seg;
        #pragma unroll
        for (int i = 0; i < 4; i++) {
            float4 q = *(const float4*)(qp + i * 4);
            *(float4*)(op + i * 4) = q;
            float f0 = q.x - xv[i].x, f1 = q.y - xv[i].y;
            float f2 = q.z - xv[i].z, f3 = q.w - xv[i].w;
            lsum = fmaf(f0, f0, lsum); lsum = fmaf(f1, f1, lsum);
            lsum = fmaf(f2, f2, lsum); lsum = fmaf(f3, f3, lsum);
        }
    }
    __syncthreads();

    // ---- exact fp32 re-argmin for flagged rows (rare, block-uniform) ----
    const int nf = cnt;
    for (int fi = 0; fi < nf; fi++) {
        const int r = flist_l[fi];
        if (tid < 32) ((float4*)xrow)[tid] = ((const float4*)(x + (size_t)(row0 + r) * DD))[tid];
        __syncthreads();
        int c0 = tid * 8;
        float s[8];
        #pragma unroll
        for (int j = 0; j < 8; j++) s[j] = 0.f;
        #pragma unroll 8
        for (int d = 0; d < DD; d++) {
            float xd = xrow[d];
            float4 ev0 = *(const float4*)(e + (size_t)d * KC + c0);
            float4 ev1 = *(const float4*)(e + (size_t)d * KC + c0 + 4);
            s[0] = fmaf(xd, ev0.x, s[0]); s[1] = fmaf(xd, ev0.y, s[1]);
            s[2] = fmaf(xd, ev0.z, s[2]); s[3] = fmaf(xd, ev0.w, s[3]);
            s[4] = fmaf(xd, ev1.x, s[4]); s[5] = fmaf(xd, ev1.y, s[5]);
            s[6] = fmaf(xd, ev1.z, s[6]); s[7] = fmaf(xd, ev1.w, s[7]);
        }
        float bv = FLT_BIG; int bi = 0x7fffffff;
        #pragma unroll
        for (int j = 0; j < 8; j++) {
            float dv = s2g[c0 + j] - 2.f * s[j];
            if (dv < bv) { bv = dv; bi = c0 + j; }
        }
        rv[tid] = bv; ri[tid] = bi;
        __syncthreads();
        if (tid == 0) {
            float b = rv[0]; int bidx = ri[0];
            for (int t = 1; t < 128; t++)
                if (rv[t] < b) { b = rv[t]; bidx = ri[t]; }
            kfix = bidx;
        }
        __syncthreads();
        {
            float q = eT[(size_t)kfix * DD + tid];
            float xd = xrow[tid];
            out_q[(size_t)(row0 + r) * DD + tid] = q;
            float f = q - xd;
            lsum = fmaf(f, f, lsum);
        }
        __syncthreads();
    }

    // ---- per-block partial loss: plain store, no atomics, no fence ----
    #pragma unroll
    for (int off = 32; off > 0; off >>= 1) lsum += __shfl_down(lsum, off, 64);
    if (lane == 0) wsum[w] = lsum;
    __syncthreads();
    if (tid == 0)
        partial[blockIdx.x] = (double)(wsum[0] + wsum[1]);
}

// ================= fin: sum 2048 partials, write loss =================
__global__ __launch_bounds__(256) void k_fin(const double* __restrict__ partial,
                                             float* __restrict__ out_loss) {
    __shared__ double wred[4];
    const int tid = threadIdx.x;
    const int w = tid >> 6, lane = tid & 63;
    double s = 0.0;
    #pragma unroll
    for (int i = 0; i < 8; i++) s += partial[i * 256 + tid];
    #pragma unroll
    for (int off = 32; off > 0; off >>= 1)
        s += __shfl_down(s, off, 64);
    if (lane == 0) wred[w] = s;
    __syncthreads();
    if (tid == 0) {
        double m = ((wred[0] + wred[1]) + (wred[2] + wred[3])) / 4194304.0;
        out_loss[0] = (float)(0.25 * m + m);
    }
}

extern "C" void kernel_launch(void* const* d_in, const int* in_sizes, int n_in,
                              void* d_out, int out_size, void* d_ws, size_t ws_size,
                              hipStream_t stream) {
    const float* x = (const float*)d_in[0];
    const float* e = (const float*)d_in[1];
    float* out_q      = (float*)d_out;
    float* out_loss   = out_q + (size_t)NROWS * DD;
    float* out_scales = out_loss + 1;

    char* ws = (char*)d_ws;
    float*  s2g            = (float*)(ws + 1024);
    float*  eT             = (float*)(ws + 8192);
    unsigned short* a_sw   = (unsigned short*)(ws + 532480);
    float*  pv0            = (float*)(ws + 1056768);
    float*  pv1            = (float*)(ws + 2105344);
    int*    pi0            = (int*)(ws + 3153920);
    double* partial        = (double*)(ws + 4202496);

    k_prep_cd<<<644, 256, 0, stream>>>(e, a_sw, eT, s2g, out_scales);
    k_main<<<2048, 256, 0, stream>>>(x, a_sw, s2g, pv0, pv1, pi0);
    k_post<<<NROWS / 16, 128, 0, stream>>>(x, e, eT, s2g, pv0, pv1, pi0, out_q, partial);
    k_fin<<<1, 256, 0, stream>>>(partial, out_loss);
}